// Round 3
// baseline (1934.804 us; speedup 1.0000x reference)
//
#include <hip/hip_runtime.h>

#define ALPHA_F 0.1f
#define DEPTH 10
#define FEATS 512
#define HID 64
#define CLS 32

// ---------------- degree count (in-degree over dst) ----------------
__global__ __launch_bounds__(256) void k_deg(const int* __restrict__ dst, int E, int N,
                                             unsigned* __restrict__ deg) {
  int i = blockIdx.x * 256 + threadIdx.x;
  if (i >= E) return;
  int d = dst[i];
  if ((unsigned)d < (unsigned)N) atomicAdd(&deg[d], 1u);
}

// ---------------- exclusive scan over deg -> rowst[0..N] (single block) ----------------
__global__ __launch_bounds__(1024) void k_scan(const unsigned* __restrict__ deg, int N,
                                               unsigned* __restrict__ rowst) {
  __shared__ unsigned sums[1024];
  int t = threadIdx.x;
  int chunk = (N + 1023) >> 10;
  int beg = t * chunk;
  int end = min(beg + chunk, N);
  unsigned s = 0;
  for (int i = beg; i < end; ++i) s += deg[i];
  sums[t] = s;
  __syncthreads();
  for (int off = 1; off < 1024; off <<= 1) {
    unsigned v = (t >= off) ? sums[t - off] : 0u;
    __syncthreads();
    sums[t] += v;
    __syncthreads();
  }
  unsigned pre = (t == 0) ? 0u : sums[t - 1];
  for (int i = beg; i < end; ++i) { rowst[i] = pre; pre += deg[i]; }
  if (t == 1023) rowst[N] = pre;  // last thread's pre == grand total
}

// ---------------- CSR fill: col only (cnt pre-seeded with rowst) ----------------
__global__ __launch_bounds__(256) void k_fill(const int* __restrict__ src,
                                              const int* __restrict__ dst, int E, int N,
                                              unsigned* __restrict__ cnt,
                                              int* __restrict__ col) {
  int e = blockIdx.x * 256 + threadIdx.x;
  if (e >= E) return;
  int s = src[e];
  int d = dst[e];
  if ((unsigned)s >= (unsigned)N || (unsigned)d >= (unsigned)N) return;  // safety guard
  unsigned slot = atomicAdd(&cnt[d], 1u);
  col[slot] = s;
}

// ---------------- fused MLP: h0 = relu(x@W1+b1)@W2+b2, plus scaled-state prep ----------
// Writes h0, u0 = rs*h0 (initial scaled state), rs[row] = rsqrt(max(deg,1)).
__global__ __launch_bounds__(256) void k_mlp(const float* __restrict__ x,
                                             const float* __restrict__ W1,
                                             const float* __restrict__ b1,
                                             const float* __restrict__ W2,
                                             const float* __restrict__ b2,
                                             const unsigned* __restrict__ deg,
                                             float* __restrict__ h0,
                                             float* __restrict__ u0,
                                             float* __restrict__ rs, int N) {
  __shared__ float XHs[64 * 65];   // Xs (stride 64) during GEMM1, Hs (stride 65) after
  __shared__ float Ws[64 * 64];    // W1 k-chunk
  __shared__ float W2s[64 * 32];
  __shared__ float b1s[64];
  __shared__ float b2s[32];
  int t = threadIdx.x;
  int m0 = blockIdx.x * 64;

  for (int i = t; i < 64 * 32; i += 256) W2s[i] = W2[i];
  if (t < 64) b1s[t] = b1[t];
  if (t < 32) b2s[t] = b2[t];

  int c = t & 31;   // col pair base (c, c+32)
  int h = t >> 5;   // row group 0..7 -> rows h*8+i
  float acc[8][2];
#pragma unroll
  for (int i = 0; i < 8; ++i) { acc[i][0] = 0.f; acc[i][1] = 0.f; }

  for (int k0 = 0; k0 < FEATS; k0 += 64) {
    __syncthreads();
    // stage X tile [64 rows][64 k] and W1 tile [64 k][64 c]: 1024 float4 each
#pragma unroll
    for (int j = 0; j < 4; ++j) {
      int F = j * 256 + t;          // float4 index 0..1023
      int r = F >> 4, q = F & 15;
      int row = m0 + r;
      float4 v = make_float4(0.f, 0.f, 0.f, 0.f);
      if (row < N) v = *(const float4*)(x + (size_t)row * FEATS + k0 + q * 4);
      *(float4*)(XHs + r * 64 + q * 4) = v;
      float4 w = *(const float4*)(W1 + (size_t)(k0 + r) * 64 + q * 4);
      *(float4*)(Ws + r * 64 + q * 4) = w;
    }
    __syncthreads();
#pragma unroll
    for (int k4 = 0; k4 < 16; ++k4) {
      int k = k4 * 4;
      float4 xv[8];
#pragma unroll
      for (int i = 0; i < 8; ++i) xv[i] = *(const float4*)(XHs + (h * 8 + i) * 64 + k);
#pragma unroll
      for (int j = 0; j < 4; ++j) {
        float w0 = Ws[(k + j) * 64 + c];
        float w1 = Ws[(k + j) * 64 + c + 32];
#pragma unroll
        for (int i = 0; i < 8; ++i) {
          float xx = ((const float*)&xv[i])[j];
          acc[i][0] += xx * w0;
          acc[i][1] += xx * w1;
        }
      }
    }
  }
  __syncthreads();
  // bias + relu -> Hs (stride 65 to dodge bank conflicts)
#pragma unroll
  for (int i = 0; i < 8; ++i) {
    int r = h * 8 + i;
    float v0 = acc[i][0] + b1s[c];
    float v1 = acc[i][1] + b1s[c + 32];
    XHs[r * 65 + c] = v0 > 0.f ? v0 : 0.f;
    XHs[r * 65 + c + 32] = v1 > 0.f ? v1 : 0.f;
  }
  __syncthreads();
  // layer 2: thread -> class cc = t&31, rows h*8+i; fused scaled-state prep
  int cc = t & 31;
#pragma unroll
  for (int i = 0; i < 8; ++i) {
    int r = h * 8 + i;
    float s = b2s[cc];
#pragma unroll
    for (int k = 0; k < 64; ++k) s += XHs[r * 65 + k] * W2s[k * 32 + cc];
    int row = m0 + r;
    if (row < N) {
      float dv = (float)deg[row];
      float rsv = rsqrtf(fmaxf(dv, 1.0f));
      h0[(size_t)row * CLS + cc] = s;
      u0[(size_t)row * CLS + cc] = rsv * s;
      if (cc == 0) rs[row] = rsv;
    }
  }
}

// ---------------- one APPNP step on scaled state u = rs .* h ----------------
// non-last: u_out[d] = 0.1*rs[d]*h0[d] + 0.9*rs[d]^2 * sum_e u_in[col[e]]
// last:     out[d]   = 0.1*h0[d]       + 0.9*rs[d]   * sum_e u_in[col[e]]
// 8 lanes per node, each lane owns 4 classes (float4).
template <bool LAST>
__global__ __launch_bounds__(256) void k_prop(const float* __restrict__ u_in,
                                              const float* __restrict__ h0,
                                              const float* __restrict__ rs,
                                              const unsigned* __restrict__ rowst,
                                              const int* __restrict__ col,
                                              float* __restrict__ out, int N) {
  int t = blockIdx.x * 256 + threadIdx.x;
  int node = t >> 3;
  if (node >= N) return;
  int l = t & 7;
  unsigned beg = rowst[node];
  unsigned end = rowst[node + 1];
  float a0 = 0.f, a1 = 0.f, a2 = 0.f, a3 = 0.f;
#pragma unroll 4
  for (unsigned e = beg; e < end; ++e) {
    int s = col[e];
    float4 v = *(const float4*)(u_in + (size_t)s * CLS + l * 4);
    a0 += v.x; a1 += v.y; a2 += v.z; a3 += v.w;
  }
  float rsv = rs[node];
  float4 h0v = *(const float4*)(h0 + (size_t)node * CLS + l * 4);
  float ca, cb;
  if (LAST) { ca = ALPHA_F; cb = (1.0f - ALPHA_F) * rsv; }
  else      { ca = ALPHA_F * rsv; cb = (1.0f - ALPHA_F) * rsv * rsv; }
  float4 o = make_float4(ca * h0v.x + cb * a0, ca * h0v.y + cb * a1,
                         ca * h0v.z + cb * a2, ca * h0v.w + cb * a3);
  *(float4*)(out + (size_t)node * CLS + l * 4) = o;
}

extern "C" void kernel_launch(void* const* d_in, const int* in_sizes, int n_in,
                              void* d_out, int out_size, void* d_ws, size_t ws_size,
                              hipStream_t stream) {
  const float* x = (const float*)d_in[0];
  const int* edges = (const int*)d_in[1];   // harness stages integer inputs as int32
  const float* W1 = (const float*)d_in[2];
  const float* b1 = (const float*)d_in[3];
  const float* W2 = (const float*)d_in[4];
  const float* b2 = (const float*)d_in[5];
  int N = in_sizes[0] / FEATS;
  int E = in_sizes[1] / 2;
  const int* src = edges;
  const int* dst = edges + E;

  char* ws = (char*)d_ws;
  auto align16 = [](size_t v) { return (v + 15) & ~(size_t)15; };
  size_t o = 0;
  unsigned* deg = (unsigned*)(ws + o);   o = align16(o + (size_t)N * 4);
  unsigned* rowst = (unsigned*)(ws + o); o = align16(o + (size_t)(N + 1) * 4);
  unsigned* cnt = (unsigned*)(ws + o);   o = align16(o + (size_t)N * 4);  // later reused as rs[]
  int* col = (int*)(ws + o);             o = align16(o + (size_t)E * 4);
  float* h0 = (float*)(ws + o);          o = align16(o + (size_t)N * CLS * 4);
  float* uA = (float*)(ws + o);          o = align16(o + (size_t)N * CLS * 4);
  float* uB = (float*)(ws + o);          o = align16(o + (size_t)N * CLS * 4);
  float* rs = (float*)cnt;               // cnt is dead after k_fill
  // total ws use ~52.4 MB (same footprint as the previously-working layout)

  hipMemsetAsync(deg, 0, (size_t)N * 4, stream);
  k_deg<<<(E + 255) / 256, 256, 0, stream>>>(dst, E, N, deg);
  k_scan<<<1, 1024, 0, stream>>>(deg, N, rowst);
  hipMemcpyAsync(cnt, rowst, (size_t)N * 4, hipMemcpyDeviceToDevice, stream);
  k_fill<<<(E + 255) / 256, 256, 0, stream>>>(src, dst, E, N, cnt, col);
  k_mlp<<<(N + 63) / 64, 256, 0, stream>>>(x, W1, b1, W2, b2, deg, h0, uA, rs, N);

  float* outF = (float*)d_out;
  const float* uin = uA;
  for (int it = 0; it < DEPTH - 1; ++it) {
    float* uo = (it & 1) ? uA : uB;
    k_prop<false><<<((N * 8) + 255) / 256, 256, 0, stream>>>(uin, h0, rs, rowst, col, uo, N);
    uin = uo;
  }
  k_prop<true><<<((N * 8) + 255) / 256, 256, 0, stream>>>(uin, h0, rs, rowst, col, outF, N);
}

// Round 4
// 1747.349 us; speedup vs baseline: 1.1073x; 1.1073x over previous
//
#include <hip/hip_runtime.h>

#define ALPHA_F 0.1f
#define DEPTH 10
#define FEATS 512
#define HID 64
#define CLS 32

// ---------------- degree count + per-edge rank (rank = old count) ----------------
__global__ __launch_bounds__(256) void k_deg(const int* __restrict__ dst, int E, int N,
                                             unsigned* __restrict__ deg,
                                             unsigned* __restrict__ rank) {
  int i = blockIdx.x * 256 + threadIdx.x;
  if (i >= E) return;
  int d = dst[i];
  unsigned r = 0;
  if ((unsigned)d < (unsigned)N) r = atomicAdd(&deg[d], 1u);
  rank[i] = r;
}

// ---------------- exclusive scan over deg -> rowst[0..N] (single block) ----------------
__global__ __launch_bounds__(1024) void k_scan(const unsigned* __restrict__ deg, int N,
                                               unsigned* __restrict__ rowst) {
  __shared__ unsigned sums[1024];
  int t = threadIdx.x;
  int chunk = (N + 1023) >> 10;
  int beg = t * chunk;
  int end = min(beg + chunk, N);
  unsigned s = 0;
  for (int i = beg; i < end; ++i) s += deg[i];
  sums[t] = s;
  __syncthreads();
  for (int off = 1; off < 1024; off <<= 1) {
    unsigned v = (t >= off) ? sums[t - off] : 0u;
    __syncthreads();
    sums[t] += v;
    __syncthreads();
  }
  unsigned pre = (t == 0) ? 0u : sums[t - 1];
  for (int i = beg; i < end; ++i) { rowst[i] = pre; pre += deg[i]; }
  if (t == 1023) rowst[N] = pre;  // last thread's pre == grand total
}

// ---------------- CSR fill, atomic-free: col[rowst[d]+rank[e]] = src[e] ----------------
__global__ __launch_bounds__(256) void k_fill(const int* __restrict__ src,
                                              const int* __restrict__ dst,
                                              const unsigned* __restrict__ rank,
                                              const unsigned* __restrict__ rowst,
                                              int E, int N,
                                              int* __restrict__ col) {
  int e = blockIdx.x * 256 + threadIdx.x;
  if (e >= E) return;
  int s = src[e];
  int d = dst[e];
  if ((unsigned)s >= (unsigned)N || (unsigned)d >= (unsigned)N) return;  // safety guard
  col[rowst[d] + rank[e]] = s;
}

// ---------------- fused MLP: h0 = relu(x@W1+b1)@W2+b2, plus scaled-state prep ----------
// Writes h0, u0 = rs*h0 (initial scaled state), rs[row] = rsqrt(max(deg,1)).
__global__ __launch_bounds__(256) void k_mlp(const float* __restrict__ x,
                                             const float* __restrict__ W1,
                                             const float* __restrict__ b1,
                                             const float* __restrict__ W2,
                                             const float* __restrict__ b2,
                                             const unsigned* __restrict__ deg,
                                             float* __restrict__ h0,
                                             float* __restrict__ u0,
                                             float* __restrict__ rs, int N) {
  __shared__ float XHs[64 * 65];   // Xs (stride 64) during GEMM1, Hs (stride 65) after
  __shared__ float Ws[64 * 64];    // W1 k-chunk
  __shared__ float W2s[64 * 32];
  __shared__ float b1s[64];
  __shared__ float b2s[32];
  int t = threadIdx.x;
  int m0 = blockIdx.x * 64;

  for (int i = t; i < 64 * 32; i += 256) W2s[i] = W2[i];
  if (t < 64) b1s[t] = b1[t];
  if (t < 32) b2s[t] = b2[t];

  int c = t & 31;   // col pair base (c, c+32)
  int h = t >> 5;   // row group 0..7 -> rows h*8+i
  float acc[8][2];
#pragma unroll
  for (int i = 0; i < 8; ++i) { acc[i][0] = 0.f; acc[i][1] = 0.f; }

  for (int k0 = 0; k0 < FEATS; k0 += 64) {
    __syncthreads();
    // stage X tile [64 rows][64 k] and W1 tile [64 k][64 c]: 1024 float4 each
#pragma unroll
    for (int j = 0; j < 4; ++j) {
      int F = j * 256 + t;          // float4 index 0..1023
      int r = F >> 4, q = F & 15;
      int row = m0 + r;
      float4 v = make_float4(0.f, 0.f, 0.f, 0.f);
      if (row < N) v = *(const float4*)(x + (size_t)row * FEATS + k0 + q * 4);
      *(float4*)(XHs + r * 64 + q * 4) = v;
      float4 w = *(const float4*)(W1 + (size_t)(k0 + r) * 64 + q * 4);
      *(float4*)(Ws + r * 64 + q * 4) = w;
    }
    __syncthreads();
#pragma unroll
    for (int k4 = 0; k4 < 16; ++k4) {
      int k = k4 * 4;
      float4 xv[8];
#pragma unroll
      for (int i = 0; i < 8; ++i) xv[i] = *(const float4*)(XHs + (h * 8 + i) * 64 + k);
#pragma unroll
      for (int j = 0; j < 4; ++j) {
        float w0 = Ws[(k + j) * 64 + c];
        float w1 = Ws[(k + j) * 64 + c + 32];
#pragma unroll
        for (int i = 0; i < 8; ++i) {
          float xx = ((const float*)&xv[i])[j];
          acc[i][0] += xx * w0;
          acc[i][1] += xx * w1;
        }
      }
    }
  }
  __syncthreads();
  // bias + relu -> Hs (stride 65 to dodge bank conflicts)
#pragma unroll
  for (int i = 0; i < 8; ++i) {
    int r = h * 8 + i;
    float v0 = acc[i][0] + b1s[c];
    float v1 = acc[i][1] + b1s[c + 32];
    XHs[r * 65 + c] = v0 > 0.f ? v0 : 0.f;
    XHs[r * 65 + c + 32] = v1 > 0.f ? v1 : 0.f;
  }
  __syncthreads();
  // layer 2: thread -> class cc = t&31, rows h*8+i; fused scaled-state prep
  int cc = t & 31;
#pragma unroll
  for (int i = 0; i < 8; ++i) {
    int r = h * 8 + i;
    float s = b2s[cc];
#pragma unroll
    for (int k = 0; k < 64; ++k) s += XHs[r * 65 + k] * W2s[k * 32 + cc];
    int row = m0 + r;
    if (row < N) {
      float dv = (float)deg[row];
      float rsv = rsqrtf(fmaxf(dv, 1.0f));
      h0[(size_t)row * CLS + cc] = s;
      u0[(size_t)row * CLS + cc] = rsv * s;
      if (cc == 0) rs[row] = rsv;
    }
  }
}

// ---------------- one APPNP step on scaled state u = rs .* h ----------------
// non-last: u_out[d] = 0.1*rs[d]*h0[d] + 0.9*rs[d]^2 * sum_e u_in[col[e]]
// last:     out[d]   = 0.1*h0[d]       + 0.9*rs[d]   * sum_e u_in[col[e]]
// 8 lanes per node, each lane owns 4 classes (float4). Manual 8-deep batch for ILP.
template <bool LAST>
__global__ __launch_bounds__(256) void k_prop(const float* __restrict__ u_in,
                                              const float* __restrict__ h0,
                                              const float* __restrict__ rs,
                                              const unsigned* __restrict__ rowst,
                                              const int* __restrict__ col,
                                              float* __restrict__ out, int N) {
  int t = blockIdx.x * 256 + threadIdx.x;
  int node = t >> 3;
  if (node >= N) return;
  int l = t & 7;
  unsigned beg = rowst[node];
  unsigned end = rowst[node + 1];
  const float* up = u_in + l * 4;
  float a0 = 0.f, a1 = 0.f, a2 = 0.f, a3 = 0.f;
  float b0 = 0.f, b1v = 0.f, b2v = 0.f, b3 = 0.f;
  unsigned e = beg;
  for (; e + 8 <= end; e += 8) {
    int s0 = col[e + 0], s1 = col[e + 1], s2 = col[e + 2], s3 = col[e + 3];
    int s4 = col[e + 4], s5 = col[e + 5], s6 = col[e + 6], s7 = col[e + 7];
    float4 v0 = *(const float4*)(up + (size_t)s0 * CLS);
    float4 v1 = *(const float4*)(up + (size_t)s1 * CLS);
    float4 v2 = *(const float4*)(up + (size_t)s2 * CLS);
    float4 v3 = *(const float4*)(up + (size_t)s3 * CLS);
    float4 v4 = *(const float4*)(up + (size_t)s4 * CLS);
    float4 v5 = *(const float4*)(up + (size_t)s5 * CLS);
    float4 v6 = *(const float4*)(up + (size_t)s6 * CLS);
    float4 v7 = *(const float4*)(up + (size_t)s7 * CLS);
    a0 += v0.x + v1.x; a1 += v0.y + v1.y; a2 += v0.z + v1.z; a3 += v0.w + v1.w;
    b0 += v2.x + v3.x; b1v += v2.y + v3.y; b2v += v2.z + v3.z; b3 += v2.w + v3.w;
    a0 += v4.x + v5.x; a1 += v4.y + v5.y; a2 += v4.z + v5.z; a3 += v4.w + v5.w;
    b0 += v6.x + v7.x; b1v += v6.y + v7.y; b2v += v6.z + v7.z; b3 += v6.w + v7.w;
  }
  for (; e < end; ++e) {
    int s = col[e];
    float4 v = *(const float4*)(up + (size_t)s * CLS);
    a0 += v.x; a1 += v.y; a2 += v.z; a3 += v.w;
  }
  a0 += b0; a1 += b1v; a2 += b2v; a3 += b3;
  float rsv = rs[node];
  float4 h0v = *(const float4*)(h0 + (size_t)node * CLS + l * 4);
  float ca, cb;
  if (LAST) { ca = ALPHA_F; cb = (1.0f - ALPHA_F) * rsv; }
  else      { ca = ALPHA_F * rsv; cb = (1.0f - ALPHA_F) * rsv * rsv; }
  float4 o = make_float4(ca * h0v.x + cb * a0, ca * h0v.y + cb * a1,
                         ca * h0v.z + cb * a2, ca * h0v.w + cb * a3);
  *(float4*)(out + (size_t)node * CLS + l * 4) = o;
}

extern "C" void kernel_launch(void* const* d_in, const int* in_sizes, int n_in,
                              void* d_out, int out_size, void* d_ws, size_t ws_size,
                              hipStream_t stream) {
  const float* x = (const float*)d_in[0];
  const int* edges = (const int*)d_in[1];   // harness stages integer inputs as int32
  const float* W1 = (const float*)d_in[2];
  const float* b1 = (const float*)d_in[3];
  const float* W2 = (const float*)d_in[4];
  const float* b2 = (const float*)d_in[5];
  int N = in_sizes[0] / FEATS;
  int E = in_sizes[1] / 2;
  const int* src = edges;
  const int* dst = edges + E;

  char* ws = (char*)d_ws;
  auto align16 = [](size_t v) { return (v + 15) & ~(size_t)15; };
  size_t o = 0;
  unsigned* deg = (unsigned*)(ws + o);   o = align16(o + (size_t)N * 4);
  unsigned* rowst = (unsigned*)(ws + o); o = align16(o + (size_t)(N + 1) * 4);
  float* rs = (float*)(ws + o);          o = align16(o + (size_t)N * 4);
  int* col = (int*)(ws + o);             o = align16(o + (size_t)E * 4);
  float* h0 = (float*)(ws + o);          o = align16(o + (size_t)N * CLS * 4);
  float* uA = (float*)(ws + o);          o = align16(o + (size_t)N * CLS * 4);
  float* uB = (float*)(ws + o);          o = align16(o + (size_t)N * CLS * 4);
  unsigned* rank = (unsigned*)uB;        // uB is dead until prop it=0 writes it; rank dead after k_fill
  // total ws use ~52.8 MB

  hipMemsetAsync(deg, 0, (size_t)N * 4, stream);
  k_deg<<<(E + 255) / 256, 256, 0, stream>>>(dst, E, N, deg, rank);
  k_scan<<<1, 1024, 0, stream>>>(deg, N, rowst);
  k_fill<<<(E + 255) / 256, 256, 0, stream>>>(src, dst, rank, rowst, E, N, col);
  k_mlp<<<(N + 63) / 64, 256, 0, stream>>>(x, W1, b1, W2, b2, deg, h0, uA, rs, N);

  float* outF = (float*)d_out;
  const float* uin = uA;
  for (int it = 0; it < DEPTH - 1; ++it) {
    float* uo = (it & 1) ? uA : uB;   // it0 -> uB (rank already consumed), it1 -> uA, ...
    k_prop<false><<<((N * 8) + 255) / 256, 256, 0, stream>>>(uin, h0, rs, rowst, col, uo, N);
    uin = uo;
  }
  k_prop<true><<<((N * 8) + 255) / 256, 256, 0, stream>>>(uin, h0, rs, rowst, col, outF, N);
}

// Round 5
// 1151.343 us; speedup vs baseline: 1.6805x; 1.5177x over previous
//
#include <hip/hip_runtime.h>

#define ALPHA_F 0.1f
#define DEPTH 10
#define FEATS 512
#define HID 64
#define CLS 32

__device__ __forceinline__ unsigned bf16rne(float f) {
  unsigned u = __float_as_uint(f);
  return (u + 0x7fffu + ((u >> 16) & 1u)) >> 16;   // round-to-nearest-even bf16
}

// ---------------- degree count + per-edge rank (rank = old count) ----------------
__global__ __launch_bounds__(256) void k_deg(const int* __restrict__ dst, int E, int N,
                                             unsigned* __restrict__ deg,
                                             unsigned* __restrict__ rank) {
  int i = blockIdx.x * 256 + threadIdx.x;
  if (i >= E) return;
  int d = dst[i];
  unsigned r = 0;
  if ((unsigned)d < (unsigned)N) r = atomicAdd(&deg[d], 1u);
  rank[i] = r;
}

// ---------------- exclusive scan over deg -> rowst[0..N] (single block) ----------------
__global__ __launch_bounds__(1024) void k_scan(const unsigned* __restrict__ deg, int N,
                                               unsigned* __restrict__ rowst) {
  __shared__ unsigned sums[1024];
  int t = threadIdx.x;
  int chunk = (N + 1023) >> 10;
  int beg = t * chunk;
  int end = min(beg + chunk, N);
  unsigned s = 0;
  for (int i = beg; i < end; ++i) s += deg[i];
  sums[t] = s;
  __syncthreads();
  for (int off = 1; off < 1024; off <<= 1) {
    unsigned v = (t >= off) ? sums[t - off] : 0u;
    __syncthreads();
    sums[t] += v;
    __syncthreads();
  }
  unsigned pre = (t == 0) ? 0u : sums[t - 1];
  for (int i = beg; i < end; ++i) { rowst[i] = pre; pre += deg[i]; }
  if (t == 1023) rowst[N] = pre;  // last thread's pre == grand total
}

// ---------------- CSR fill, atomic-free: col[rowst[d]+rank[e]] = src[e] ----------------
__global__ __launch_bounds__(256) void k_fill(const int* __restrict__ src,
                                              const int* __restrict__ dst,
                                              const unsigned* __restrict__ rank,
                                              const unsigned* __restrict__ rowst,
                                              int E, int N,
                                              int* __restrict__ col) {
  int e = blockIdx.x * 256 + threadIdx.x;
  if (e >= E) return;
  int s = src[e];
  int d = dst[e];
  if ((unsigned)s >= (unsigned)N || (unsigned)d >= (unsigned)N) return;  // safety guard
  col[rowst[d] + rank[e]] = s;
}

// ---------------- fused MLP: h0 = relu(x@W1+b1)@W2+b2, plus scaled-state prep ----------
// Writes h0 (f32), u0 = bf16(rs*h0) (initial scaled state), rs[row] = rsqrt(max(deg,1)).
// W1 is NOT LDS-staged: 131 KB, L2-resident, wave-dedup'd loads. LDS ~25 KB -> 6 blocks/CU.
__global__ __launch_bounds__(256) void k_mlp(const float* __restrict__ x,
                                             const float* __restrict__ W1,
                                             const float* __restrict__ b1,
                                             const float* __restrict__ W2,
                                             const float* __restrict__ b2,
                                             const unsigned* __restrict__ deg,
                                             float* __restrict__ h0,
                                             unsigned short* __restrict__ u0,
                                             float* __restrict__ rs, int N) {
  __shared__ float XHs[64 * 65];   // Xs (stride 64) during GEMM1, Hs (stride 65) after
  __shared__ float W2s[64 * 32];
  __shared__ float b1s[64];
  __shared__ float b2s[32];
  int t = threadIdx.x;
  int m0 = blockIdx.x * 64;

  for (int i = t; i < 64 * 32; i += 256) W2s[i] = W2[i];
  if (t < 64) b1s[t] = b1[t];
  if (t < 32) b2s[t] = b2[t];

  int c = t & 31;   // col pair base (c, c+32)
  int h = t >> 5;   // row group 0..7 -> rows h*8+i
  float acc[8][2];
#pragma unroll
  for (int i = 0; i < 8; ++i) { acc[i][0] = 0.f; acc[i][1] = 0.f; }

  for (int k0 = 0; k0 < FEATS; k0 += 64) {
    __syncthreads();
    // stage X tile [64 rows][64 k]: 512 float4 over 256 threads
#pragma unroll
    for (int j = 0; j < 2; ++j) {
      int F = j * 256 + t;          // float4 index 0..511
      int r = F >> 3, q = F & 7;    // row 0..63, quad 0..7 (q*8 floats.. q*4? -> 8 quads of 8 floats? no: 64 floats = 16 float4; 512 idx/64rows = 8 per row)
      int row = m0 + r;
      float4 v = make_float4(0.f, 0.f, 0.f, 0.f);
      if (row < N) v = *(const float4*)(x + (size_t)row * FEATS + k0 + q * 8);
      *(float4*)(XHs + r * 64 + q * 8) = v;
      float4 v2 = make_float4(0.f, 0.f, 0.f, 0.f);
      if (row < N) v2 = *(const float4*)(x + (size_t)row * FEATS + k0 + q * 8 + 4);
      *(float4*)(XHs + r * 64 + q * 8 + 4) = v2;
    }
    __syncthreads();
    const float* W1p = W1 + (size_t)k0 * 64;
#pragma unroll
    for (int k4 = 0; k4 < 16; ++k4) {
      int k = k4 * 4;
      float4 xv[8];
#pragma unroll
      for (int i = 0; i < 8; ++i) xv[i] = *(const float4*)(XHs + (h * 8 + i) * 64 + k);
#pragma unroll
      for (int j = 0; j < 4; ++j) {
        float w0 = W1p[(k + j) * 64 + c];        // L2-resident, dedup'd across waves
        float w1 = W1p[(k + j) * 64 + c + 32];
#pragma unroll
        for (int i = 0; i < 8; ++i) {
          float xx = ((const float*)&xv[i])[j];
          acc[i][0] += xx * w0;
          acc[i][1] += xx * w1;
        }
      }
    }
  }
  __syncthreads();
  // bias + relu -> Hs (stride 65 to dodge bank conflicts)
#pragma unroll
  for (int i = 0; i < 8; ++i) {
    int r = h * 8 + i;
    float v0 = acc[i][0] + b1s[c];
    float v1 = acc[i][1] + b1s[c + 32];
    XHs[r * 65 + c] = v0 > 0.f ? v0 : 0.f;
    XHs[r * 65 + c + 32] = v1 > 0.f ? v1 : 0.f;
  }
  __syncthreads();
  // layer 2: thread -> class cc = t&31, rows h*8+i; fused scaled-state prep
  int cc = t & 31;
#pragma unroll
  for (int i = 0; i < 8; ++i) {
    int r = h * 8 + i;
    float s = b2s[cc];
#pragma unroll
    for (int k = 0; k < 64; ++k) s += XHs[r * 65 + k] * W2s[k * 32 + cc];
    int row = m0 + r;
    if (row < N) {
      float dv = (float)deg[row];
      float rsv = rsqrtf(fmaxf(dv, 1.0f));
      h0[(size_t)row * CLS + cc] = s;
      u0[(size_t)row * CLS + cc] = (unsigned short)bf16rne(rsv * s);
      if (cc == 0) rs[row] = rsv;
    }
  }
}

// ---------------- one APPNP step on bf16 scaled state u = bf16(rs .* h) ----------------
// non-last: u_out[d] = bf16( 0.1*rs[d]*h0[d] + 0.9*rs[d]^2 * sum_e u_in[col[e]] )
// last:     out[d]   =       0.1*h0[d]       + 0.9*rs[d]   * sum_e u_in[col[e]]  (f32)
// 8 lanes per node; u row = 16 uints (32 bf16, 64 B); lane owns uint2 (4 classes).
template <bool LAST>
__global__ __launch_bounds__(256) void k_prop(const unsigned* __restrict__ u_in,
                                              const float* __restrict__ h0,
                                              const float* __restrict__ rs,
                                              const unsigned* __restrict__ rowst,
                                              const int* __restrict__ col,
                                              void* __restrict__ out, int N) {
  int t = blockIdx.x * 256 + threadIdx.x;
  int node = t >> 3;
  if (node >= N) return;
  int l = t & 7;
  unsigned beg = rowst[node];
  unsigned end = rowst[node + 1];
  const unsigned* up = u_in + l * 2;   // lane's uint2 within a 16-uint row
  float a0 = 0.f, a1 = 0.f, a2 = 0.f, a3 = 0.f;
  float b0 = 0.f, b1v = 0.f, b2v = 0.f, b3 = 0.f;
  unsigned e = beg;
  for (; e + 8 <= end; e += 8) {
    int s0 = col[e + 0], s1 = col[e + 1], s2 = col[e + 2], s3 = col[e + 3];
    int s4 = col[e + 4], s5 = col[e + 5], s6 = col[e + 6], s7 = col[e + 7];
    uint2 q0 = *(const uint2*)(up + (size_t)s0 * 16);
    uint2 q1 = *(const uint2*)(up + (size_t)s1 * 16);
    uint2 q2 = *(const uint2*)(up + (size_t)s2 * 16);
    uint2 q3 = *(const uint2*)(up + (size_t)s3 * 16);
    uint2 q4 = *(const uint2*)(up + (size_t)s4 * 16);
    uint2 q5 = *(const uint2*)(up + (size_t)s5 * 16);
    uint2 q6 = *(const uint2*)(up + (size_t)s6 * 16);
    uint2 q7 = *(const uint2*)(up + (size_t)s7 * 16);
    a0 += __uint_as_float(q0.x << 16) + __uint_as_float(q1.x << 16);
    a1 += __uint_as_float(q0.x & 0xffff0000u) + __uint_as_float(q1.x & 0xffff0000u);
    a2 += __uint_as_float(q0.y << 16) + __uint_as_float(q1.y << 16);
    a3 += __uint_as_float(q0.y & 0xffff0000u) + __uint_as_float(q1.y & 0xffff0000u);
    b0 += __uint_as_float(q2.x << 16) + __uint_as_float(q3.x << 16);
    b1v += __uint_as_float(q2.x & 0xffff0000u) + __uint_as_float(q3.x & 0xffff0000u);
    b2v += __uint_as_float(q2.y << 16) + __uint_as_float(q3.y << 16);
    b3 += __uint_as_float(q2.y & 0xffff0000u) + __uint_as_float(q3.y & 0xffff0000u);
    a0 += __uint_as_float(q4.x << 16) + __uint_as_float(q5.x << 16);
    a1 += __uint_as_float(q4.x & 0xffff0000u) + __uint_as_float(q5.x & 0xffff0000u);
    a2 += __uint_as_float(q4.y << 16) + __uint_as_float(q5.y << 16);
    a3 += __uint_as_float(q4.y & 0xffff0000u) + __uint_as_float(q5.y & 0xffff0000u);
    b0 += __uint_as_float(q6.x << 16) + __uint_as_float(q7.x << 16);
    b1v += __uint_as_float(q6.x & 0xffff0000u) + __uint_as_float(q7.x & 0xffff0000u);
    b2v += __uint_as_float(q6.y << 16) + __uint_as_float(q7.y << 16);
    b3 += __uint_as_float(q6.y & 0xffff0000u) + __uint_as_float(q7.y & 0xffff0000u);
  }
  for (; e < end; ++e) {
    int s = col[e];
    uint2 q = *(const uint2*)(up + (size_t)s * 16);
    a0 += __uint_as_float(q.x << 16);
    a1 += __uint_as_float(q.x & 0xffff0000u);
    a2 += __uint_as_float(q.y << 16);
    a3 += __uint_as_float(q.y & 0xffff0000u);
  }
  a0 += b0; a1 += b1v; a2 += b2v; a3 += b3;
  float rsv = rs[node];
  float4 h0v = *(const float4*)(h0 + (size_t)node * CLS + l * 4);
  if (LAST) {
    float ca = ALPHA_F, cb = (1.0f - ALPHA_F) * rsv;
    float4 o = make_float4(ca * h0v.x + cb * a0, ca * h0v.y + cb * a1,
                           ca * h0v.z + cb * a2, ca * h0v.w + cb * a3);
    *(float4*)((float*)out + (size_t)node * CLS + l * 4) = o;
  } else {
    float ca = ALPHA_F * rsv, cb = (1.0f - ALPHA_F) * rsv * rsv;
    float o0 = ca * h0v.x + cb * a0, o1 = ca * h0v.y + cb * a1;
    float o2 = ca * h0v.z + cb * a2, o3 = ca * h0v.w + cb * a3;
    uint2 p;
    p.x = bf16rne(o0) | (bf16rne(o1) << 16);
    p.y = bf16rne(o2) | (bf16rne(o3) << 16);
    *(uint2*)((unsigned*)out + (size_t)node * 16 + l * 2) = p;
  }
}

extern "C" void kernel_launch(void* const* d_in, const int* in_sizes, int n_in,
                              void* d_out, int out_size, void* d_ws, size_t ws_size,
                              hipStream_t stream) {
  const float* x = (const float*)d_in[0];
  const int* edges = (const int*)d_in[1];   // harness stages integer inputs as int32
  const float* W1 = (const float*)d_in[2];
  const float* b1 = (const float*)d_in[3];
  const float* W2 = (const float*)d_in[4];
  const float* b2 = (const float*)d_in[5];
  int N = in_sizes[0] / FEATS;
  int E = in_sizes[1] / 2;
  const int* src = edges;
  const int* dst = edges + E;

  char* ws = (char*)d_ws;
  auto align64 = [](size_t v) { return (v + 63) & ~(size_t)63; };
  size_t o = 0;
  unsigned* deg = (unsigned*)(ws + o);   o = align64(o + (size_t)N * 4);
  unsigned* rowst = (unsigned*)(ws + o); o = align64(o + (size_t)(N + 1) * 4);
  float* rs = (float*)(ws + o);          o = align64(o + (size_t)N * 4);
  int* col = (int*)(ws + o);             o = align64(o + (size_t)E * 4);
  float* h0 = (float*)(ws + o);          o = align64(o + (size_t)N * CLS * 4);
  unsigned* uA = (unsigned*)(ws + o);    o = align64(o + (size_t)N * CLS * 2);  // bf16 state
  unsigned* uB = (unsigned*)(ws + o);    o = align64(o + (size_t)N * CLS * 2);  // bf16 state
  unsigned* rank = (unsigned*)h0;        // h0 written only after k_fill consumed rank (12.8MB each)
  // total ws use ~39.6 MB

  hipMemsetAsync(deg, 0, (size_t)N * 4, stream);
  k_deg<<<(E + 255) / 256, 256, 0, stream>>>(dst, E, N, deg, rank);
  k_scan<<<1, 1024, 0, stream>>>(deg, N, rowst);
  k_fill<<<(E + 255) / 256, 256, 0, stream>>>(src, dst, rank, rowst, E, N, col);
  k_mlp<<<(N + 63) / 64, 256, 0, stream>>>(x, W1, b1, W2, b2, deg, h0,
                                           (unsigned short*)uA, rs, N);

  float* outF = (float*)d_out;
  const unsigned* uin = uA;
  for (int it = 0; it < DEPTH - 1; ++it) {
    unsigned* uo = (it & 1) ? uA : uB;
    k_prop<false><<<((N * 8) + 255) / 256, 256, 0, stream>>>(uin, h0, rs, rowst, col, uo, N);
    uin = uo;
  }
  k_prop<true><<<((N * 8) + 255) / 256, 256, 0, stream>>>(uin, h0, rs, rowst, col, outF, N);
}